// Round 10
// baseline (315.360 us; speedup 1.0000x reference)
//
#include <hip/hip_runtime.h>
#include <hip/hip_cooperative_groups.h>
#include <stdint.h>

namespace cg = cooperative_groups;

#define N_NODES 100000
#define N_EDGES 50000
#define C 128
#define NB 196        // coarse buckets: ceil(50000/256) == ceil(100000/512)
#define CAP 12288     // LDS staging entries per bucket (48KB)
#define X0_BLOCKS 25000   // N_NODES*C/2 / 256

typedef short short8 __attribute__((ext_vector_type(8)));   // 8 bf16 (4 VGPRs)
typedef float f32x4  __attribute__((ext_vector_type(4)));

// ---------- bf16 helpers ----------
__device__ __forceinline__ unsigned int bf16rne(float f) {
    unsigned int u = __float_as_uint(f);
    return (u + 0x7FFFu + ((u >> 16) & 1u)) >> 16;    // finite inputs only
}
__device__ __forceinline__ unsigned int pk_bf16(float x, float y) {
    return (bf16rne(y) << 16) | bf16rne(x);
}
__device__ __forceinline__ float bf_lo(unsigned int u) { return __uint_as_float(u << 16); }
__device__ __forceinline__ float bf_hi(unsigned int u) { return __uint_as_float(u & 0xFFFF0000u); }

// ---------- fused pre-pass: x0->bf16, W->bf16, zero coarse hist ----------
__global__ __launch_bounds__(256) void conv_all(
    const float2* __restrict__ x0, const float2* __restrict__ W,
    unsigned int* __restrict__ x0h, unsigned int* __restrict__ Whu,
    int* __restrict__ CehCnh)
{
    int bid = blockIdx.x, t = threadIdx.x;
    if (bid < X0_BLOCKS) {
        int i = bid * 256 + t;
        float2 v = x0[i];
        x0h[i] = pk_bf16(v.x, v.y);
        if (bid == 0)
            for (int k = t; k < 2 * NB; k += 256) CehCnh[k] = 0;
    } else {
        int i = (bid - X0_BLOCKS) * 256 + t;   // < C*C/2 = 8192
        float2 v = W[i];
        Whu[i] = pk_bf16(v.x, v.y);
    }
}

// ---------------- fused CSR front-end (cooperative): hist -> scan -> partition --
// Each block keeps its 4096 index pairs in registers across the phases.
// e-side pair: (e & 255) | (n << 8) ; n-side pair: (n & 511) | (e << 9)
__global__ __launch_bounds__(256) void csr_front(
    const int* __restrict__ nidx, const int* __restrict__ eidx,
    int* __restrict__ Ceh, int* __restrict__ Cnh,
    int* __restrict__ Cecur, int* __restrict__ Cncur,
    unsigned int* __restrict__ pe, unsigned int* __restrict__ pn, int nnz)
{
    cg::grid_group grid = cg::this_grid();
    __shared__ int he[NB], hn[NB], be[NB], bn[NB];
    __shared__ int s[256];
    int t = threadIdx.x;
    int chunk0 = blockIdx.x * 4096;

    int ev[16], nv[16];
#pragma unroll
    for (int j = 0; j < 16; ++j) {
        int i = chunk0 + j * 256 + t;
        ev[j] = (i < nnz) ? eidx[i] : -1;
        nv[j] = (i < nnz) ? nidx[i] : -1;
    }
    for (int k = t; k < NB; k += 256) { he[k] = 0; hn[k] = 0; }
    __syncthreads();
#pragma unroll
    for (int j = 0; j < 16; ++j) {
        if (ev[j] >= 0) {
            atomicAdd(&he[ev[j] >> 8], 1);
            atomicAdd(&hn[nv[j] >> 9], 1);
        }
    }
    __syncthreads();
    for (int k = t; k < NB; k += 256) {
        if (he[k]) atomicAdd(&Ceh[k], he[k]);
        if (hn[k]) atomicAdd(&Cnh[k], hn[k]);
    }
    grid.sync();

    if (blockIdx.x == 0) {        // tiny exclusive scan -> bucket base cursors
        int v = (t < NB) ? Ceh[t] : 0;
        s[t] = v; __syncthreads();
        for (int d = 1; d < 256; d <<= 1) {
            int u = (t >= d) ? s[t - d] : 0;
            __syncthreads(); s[t] += u; __syncthreads();
        }
        if (t < NB) Cecur[t] = s[t] - v;
        __syncthreads();
        v = (t < NB) ? Cnh[t] : 0;
        s[t] = v; __syncthreads();
        for (int d = 1; d < 256; d <<= 1) {
            int u = (t >= d) ? s[t - d] : 0;
            __syncthreads(); s[t] += u; __syncthreads();
        }
        if (t < NB) Cncur[t] = s[t] - v;
    }
    grid.sync();

    // reserve ranges (he/hn still hold this block's counts), then scatter
    for (int k = t; k < NB; k += 256) {
        be[k] = he[k] ? atomicAdd(&Cecur[k], he[k]) : 0;
        bn[k] = hn[k] ? atomicAdd(&Cncur[k], hn[k]) : 0;
        he[k] = 0; hn[k] = 0;
    }
    __syncthreads();
#pragma unroll
    for (int j = 0; j < 16; ++j) {
        if (ev[j] >= 0) {
            int e = ev[j], n = nv[j];
            int re = atomicAdd(&he[e >> 8], 1);
            pe[be[e >> 8] + re] = (unsigned int)((e & 255) | (n << 8));
            int rn = atomicAdd(&hn[n >> 9], 1);
            pn[bn[n >> 9] + rn] = (unsigned int)((n & 511) | (e << 9));
        }
    }
}

// ---------------- non-coop fallback: hist / scan / partition ----------------
__global__ __launch_bounds__(256) void coarse_hist(
    const int* __restrict__ nidx, const int* __restrict__ eidx,
    int* __restrict__ Ceh, int* __restrict__ Cnh, int nnz)
{
    __shared__ int he[NB], hn[NB];
    int t = threadIdx.x;
    int chunk0 = blockIdx.x * 4096;
    for (int k = t; k < NB; k += 256) { he[k] = 0; hn[k] = 0; }
    __syncthreads();
#pragma unroll 4
    for (int j = 0; j < 16; ++j) {
        int i = chunk0 + j * 256 + t;
        if (i < nnz) {
            atomicAdd(&he[eidx[i] >> 8], 1);
            atomicAdd(&hn[nidx[i] >> 9], 1);
        }
    }
    __syncthreads();
    for (int k = t; k < NB; k += 256) {
        if (he[k]) atomicAdd(&Ceh[k], he[k]);
        if (hn[k]) atomicAdd(&Cnh[k], hn[k]);
    }
}

__global__ __launch_bounds__(256) void coarse_scan(
    const int* __restrict__ Ceh, const int* __restrict__ Cnh,
    int* __restrict__ Cecur, int* __restrict__ Cncur)
{
    __shared__ int s[256];
    int t = threadIdx.x;
    int v = (t < NB) ? Ceh[t] : 0;
    s[t] = v; __syncthreads();
    for (int d = 1; d < 256; d <<= 1) {
        int u = (t >= d) ? s[t - d] : 0;
        __syncthreads(); s[t] += u; __syncthreads();
    }
    if (t < NB) Cecur[t] = s[t] - v;
    __syncthreads();
    v = (t < NB) ? Cnh[t] : 0;
    s[t] = v; __syncthreads();
    for (int d = 1; d < 256; d <<= 1) {
        int u = (t >= d) ? s[t - d] : 0;
        __syncthreads(); s[t] += u; __syncthreads();
    }
    if (t < NB) Cncur[t] = s[t] - v;
}

__global__ __launch_bounds__(256) void partition_kernel(
    const int* __restrict__ nidx, const int* __restrict__ eidx,
    int* __restrict__ Cecur, int* __restrict__ Cncur,
    unsigned int* __restrict__ pe, unsigned int* __restrict__ pn, int nnz)
{
    __shared__ int he[NB], hn[NB], be[NB], bn[NB];
    int t = threadIdx.x;
    int chunk0 = blockIdx.x * 4096;
    for (int k = t; k < NB; k += 256) { he[k] = 0; hn[k] = 0; }
    __syncthreads();
#pragma unroll 4
    for (int j = 0; j < 16; ++j) {
        int i = chunk0 + j * 256 + t;
        if (i < nnz) {
            atomicAdd(&he[eidx[i] >> 8], 1);
            atomicAdd(&hn[nidx[i] >> 9], 1);
        }
    }
    __syncthreads();
    for (int k = t; k < NB; k += 256) {
        be[k] = atomicAdd(&Cecur[k], he[k]);
        bn[k] = atomicAdd(&Cncur[k], hn[k]);
        he[k] = 0; hn[k] = 0;
    }
    __syncthreads();
#pragma unroll 4
    for (int j = 0; j < 16; ++j) {
        int i = chunk0 + j * 256 + t;
        if (i < nnz) {
            int e = eidx[i], n = nidx[i];
            int re = atomicAdd(&he[e >> 8], 1);
            pe[be[e >> 8] + re] = (unsigned int)((e & 255) | (n << 8));
            int rn = atomicAdd(&hn[n >> 9], 1);
            pn[bn[n >> 9] + rn] = (unsigned int)((n & 511) | (e << 9));
        }
    }
}

// ---------------- phase B2: fine hist + scan + scatter, all in LDS ----------------
__global__ __launch_bounds__(256) void bucket_scatter_ex(
    const unsigned int* __restrict__ pe, const unsigned int* __restrict__ pn,
    const int* __restrict__ Cecur, const int* __restrict__ Cncur,
    int* __restrict__ e_list, int* __restrict__ n_list,
    int* __restrict__ eoff, int* __restrict__ noff)
{
    __shared__ int cnt[512], cur[512], s[256];
    __shared__ int vals[CAP];
    bool eside = blockIdx.x < NB;
    int b = eside ? blockIdx.x : blockIdx.x - NB;
    const unsigned int* pairs = eside ? pe : pn;
    const int* endarr         = eside ? Cecur : Cncur;
    int* out                  = eside ? e_list : n_list;
    int* off                  = eside ? eoff : noff;
    int shift = eside ? 8 : 9;
    int mask  = (1 << shift) - 1;
    int kpb   = 1 << shift;
    int nkeys = eside ? N_EDGES : N_NODES;
    int key0 = b * kpb;
    int nk = nkeys - key0; if (nk > kpb) nk = kpb;
    if (nk <= 0) return;
    int start = (b == 0) ? 0 : endarr[b - 1];
    int end   = endarr[b];
    int t = threadIdx.x;

    for (int k = t; k < nk; k += 256) cnt[k] = 0;
    __syncthreads();
    for (int i = start + t; i < end; i += 256)
        atomicAdd(&cnt[(int)(pairs[i] & mask)], 1);
    __syncthreads();
    int k0 = 2 * t, k1 = 2 * t + 1;
    int c0 = (k0 < nk) ? cnt[k0] : 0;
    int c1 = (k1 < nk) ? cnt[k1] : 0;
    int local = c0 + c1;
    s[t] = local; __syncthreads();
    for (int d = 1; d < 256; d <<= 1) {
        int u = (t >= d) ? s[t - d] : 0;
        __syncthreads(); s[t] += u; __syncthreads();
    }
    int excl = s[t] - local;
    if (k0 < nk) { cur[k0] = excl;      off[key0 + k0] = start + excl; }
    if (k1 < nk) { cur[k1] = excl + c0; off[key0 + k1] = start + excl + c0; }
    if (b == NB - 1 && t == 0) off[nkeys] = end;
    __syncthreads();
    for (int i = start + t; i < end; i += 256) {
        unsigned int p = pairs[i];
        int key = (int)(p & mask);
        int val = (int)(p >> shift);
        int pos = atomicAdd(&cur[key], 1);
        if (pos < CAP) vals[pos] = val;
        else out[start + pos] = val;
    }
    __syncthreads();
    int sz = end - start; if (sz > CAP) sz = CAP;
    for (int j = t; j < sz; j += 256) out[start + j] = vals[j];
}

// ---------------- 8-deep MLP gather-sum of packed-bf16 rows ----------------
__device__ __forceinline__ float2 gather_bf16_rows(
    const unsigned int* __restrict__ src, const int* __restrict__ list,
    int s0, int s1, int lane)
{
    float ax0=0,ay0=0,ax1=0,ay1=0,ax2=0,ay2=0,ax3=0,ay3=0;
    float ax4=0,ay4=0,ax5=0,ay5=0,ax6=0,ay6=0,ax7=0,ay7=0;
    for (int base = s0; base < s1; base += 64) {
        int cnt = s1 - base; if (cnt > 64) cnt = 64;
        int my = (lane < cnt) ? list[base + lane] : 0;
        int j = 0;
        for (; j + 8 <= cnt; j += 8) {
            int g0 = __shfl(my, j+0), g1 = __shfl(my, j+1);
            int g2 = __shfl(my, j+2), g3 = __shfl(my, j+3);
            int g4 = __shfl(my, j+4), g5 = __shfl(my, j+5);
            int g6 = __shfl(my, j+6), g7 = __shfl(my, j+7);
            unsigned int u0 = src[(size_t)g0 * 64 + lane];
            unsigned int u1 = src[(size_t)g1 * 64 + lane];
            unsigned int u2 = src[(size_t)g2 * 64 + lane];
            unsigned int u3 = src[(size_t)g3 * 64 + lane];
            unsigned int u4 = src[(size_t)g4 * 64 + lane];
            unsigned int u5 = src[(size_t)g5 * 64 + lane];
            unsigned int u6 = src[(size_t)g6 * 64 + lane];
            unsigned int u7 = src[(size_t)g7 * 64 + lane];
            ax0 += bf_lo(u0); ay0 += bf_hi(u0);  ax1 += bf_lo(u1); ay1 += bf_hi(u1);
            ax2 += bf_lo(u2); ay2 += bf_hi(u2);  ax3 += bf_lo(u3); ay3 += bf_hi(u3);
            ax4 += bf_lo(u4); ay4 += bf_hi(u4);  ax5 += bf_lo(u5); ay5 += bf_hi(u5);
            ax6 += bf_lo(u6); ay6 += bf_hi(u6);  ax7 += bf_lo(u7); ay7 += bf_hi(u7);
        }
        for (; j < cnt; ++j) {
            int g = __shfl(my, j);
            unsigned int u = src[(size_t)g * 64 + lane];
            ax0 += bf_lo(u); ay0 += bf_hi(u);
        }
    }
    ax0+=ax1; ay0+=ay1; ax2+=ax3; ay2+=ay3; ax4+=ax5; ay4+=ay5; ax6+=ax7; ay6+=ay7;
    ax0+=ax2; ay0+=ay2; ax4+=ax6; ay4+=ay6;
    ax0+=ax4; ay0+=ay4;
    return make_float2(ax0, ay0);
}

// ---------------- step 1: x1[e] = sum_{n in e} x0[n] (+ bf16 copy) ----------------
__global__ __launch_bounds__(256) void seg_sum(
    const unsigned int* __restrict__ x0h, const int* __restrict__ list,
    const int* __restrict__ off, float2* __restrict__ x1,
    unsigned int* __restrict__ x1h, int nseg)
{
    int wid  = (blockIdx.x * 256 + threadIdx.x) >> 6;
    int lane = threadIdx.x & 63;
    if (wid >= nseg) return;
    float2 acc = gather_bf16_rows(x0h, list, off[wid], off[wid + 1], lane);
    x1 [(size_t)wid * 64 + lane] = acc;
    x1h[(size_t)wid * 64 + lane] = pk_bf16(acc.x, acc.y);
}

// ---------------- steps 2+3 fused: gather + MFMA GEMM ----------------
__global__ __launch_bounds__(256) void gin_fused(
    const unsigned int* __restrict__ x0h, const unsigned int* __restrict__ x1h,
    const int* __restrict__ n_list, const int* __restrict__ noff,
    const unsigned short* __restrict__ Wh, const float* __restrict__ b,
    float* __restrict__ out)
{
    __shared__ __align__(16) unsigned short ins[32][136];  // bf16, +16B pad/row
    int t = threadIdx.x;
    int lane = t & 63, w = t >> 6;
    int row0 = blockIdx.x * 32;

    for (int r = w * 8; r < w * 8 + 8; ++r) {
        int node = row0 + r;
        unsigned int bu = x0h[(size_t)node * 64 + lane];
        float2 g = gather_bf16_rows(x1h, n_list, noff[node], noff[node + 1], lane);
        g.x += bf_lo(bu); g.y += bf_hi(bu);
        *(unsigned int*)&ins[r][lane * 2] = pk_bf16(g.x, g.y);
    }
    __syncthreads();

    int mt  = w & 1;            // M-tile (16 rows)
    int ntb = (w >> 1) * 4;     // first of 4 N-tiles
    int l15  = lane & 15;
    int koff = (lane >> 4) * 8;
    int arow = mt * 16 + l15;

    f32x4 acc0 = {0,0,0,0}, acc1 = {0,0,0,0}, acc2 = {0,0,0,0}, acc3 = {0,0,0,0};
#pragma unroll
    for (int kt = 0; kt < C; kt += 32) {
        short8 a = *(const short8*)&ins[arow][kt + koff];
        short8 b0 = *(const short8*)&Wh[(size_t)((ntb + 0) * 16 + l15) * C + kt + koff];
        short8 b1 = *(const short8*)&Wh[(size_t)((ntb + 1) * 16 + l15) * C + kt + koff];
        short8 b2 = *(const short8*)&Wh[(size_t)((ntb + 2) * 16 + l15) * C + kt + koff];
        short8 b3 = *(const short8*)&Wh[(size_t)((ntb + 3) * 16 + l15) * C + kt + koff];
        acc0 = __builtin_amdgcn_mfma_f32_16x16x32_bf16(a, b0, acc0, 0, 0, 0);
        acc1 = __builtin_amdgcn_mfma_f32_16x16x32_bf16(a, b1, acc1, 0, 0, 0);
        acc2 = __builtin_amdgcn_mfma_f32_16x16x32_bf16(a, b2, acc2, 0, 0, 0);
        acc3 = __builtin_amdgcn_mfma_f32_16x16x32_bf16(a, b3, acc3, 0, 0, 0);
    }

    int drow = row0 + mt * 16 + (lane >> 4) * 4;
#pragma unroll
    for (int n = 0; n < 4; ++n) {
        f32x4 accv = (n == 0) ? acc0 : (n == 1) ? acc1 : (n == 2) ? acc2 : acc3;
        int colg = (ntb + n) * 16 + l15;
        float bias = b[colg];
#pragma unroll
        for (int j = 0; j < 4; ++j)
            out[(size_t)(drow + j) * C + colg] = accv[j] + bias;
    }
}

// ---------------- fallback atomic path ----------------
__global__ __launch_bounds__(256) void scatter_rows(
    const float4* __restrict__ src, const int* __restrict__ gather_idx,
    const int* __restrict__ scatter_idx, float* __restrict__ dst, int nnz)
{
    int gid = blockIdx.x * 256 + threadIdx.x;
    int row = gid >> 5, lane = gid & 31;
    if (row >= nnz) return;
    float4 v = src[(size_t)gather_idx[row] * 32 + lane];
    float* d = dst + (size_t)scatter_idx[row] * C + lane * 4;
    atomicAdd(d + 0, v.x); atomicAdd(d + 1, v.y);
    atomicAdd(d + 2, v.z); atomicAdd(d + 3, v.w);
}

__global__ __launch_bounds__(256) void gin_gemm(
    const float* __restrict__ x0, const float* __restrict__ m,
    const float* __restrict__ W, const float* __restrict__ b,
    float* __restrict__ out)
{
    __shared__ float Ws[32][129];
    __shared__ float insf[32][33];
    int t = threadIdx.x;
    int col = t & 127, rg = t >> 7;
    int row0 = blockIdx.x * 32;
    float acc[16];
#pragma unroll
    for (int r = 0; r < 16; ++r) acc[r] = 0.f;
    float bias = b[col];
    for (int kt = 0; kt < C; kt += 32) {
#pragma unroll
        for (int j = 0; j < 16; ++j) {
            int i = j * 256 + t, wc = i >> 5, kl = i & 31;
            Ws[kl][wc] = W[(size_t)wc * C + kt + kl];
        }
#pragma unroll
        for (int j = 0; j < 4; ++j) {
            int i = j * 256 + t, r = i >> 5, kl = i & 31;
            size_t gi = (size_t)(row0 + r) * C + kt + kl;
            insf[r][kl] = x0[gi] + m[gi];
        }
        __syncthreads();
#pragma unroll
        for (int kl = 0; kl < 32; ++kl) {
            float wv = Ws[kl][col];
#pragma unroll
            for (int r = 0; r < 16; ++r)
                acc[r] += insf[rg * 16 + r][kl] * wv;
        }
        __syncthreads();
    }
#pragma unroll
    for (int r = 0; r < 16; ++r)
        out[(size_t)(row0 + rg * 16 + r) * C + col] = acc[r] + bias;
}

extern "C" void kernel_launch(void* const* d_in, const int* in_sizes, int n_in,
                              void* d_out, int out_size, void* d_ws, size_t ws_size,
                              hipStream_t stream) {
    const float* x0 = (const float*)d_in[0];
    const int* nidx = (const int*)d_in[1];
    const int* eidx = (const int*)d_in[2];
    const float* W  = (const float*)d_in[3];
    const float* b  = (const float*)d_in[4];

    float* out0 = (float*)d_out;
    float* x1   = out0 + (size_t)N_NODES * C;
    int nnz = in_sizes[1];

    // ---- workspace layout, each region 256B-aligned (rows must not straddle
    //      extra 128B cache lines on the hot gather targets) ----
    auto align256 = [](char* q) {
        return (char*)(((uintptr_t)q + 255) & ~(uintptr_t)255);
    };
    char* p = align256((char*)d_ws);
    unsigned int* pe = (unsigned int*)p; p = align256(p + (size_t)nnz * 4);  // 4B pairs
    unsigned int* pn = (unsigned int*)p; p = align256(p + (size_t)nnz * 4);
    unsigned int* x0h = (unsigned int*)p; p = align256(p + (size_t)N_NODES * 64 * 4);
    unsigned int* x1h = (unsigned int*)p; p = align256(p + (size_t)N_EDGES * 64 * 4);
    int* e_list = (int*)p; p = align256(p + (size_t)nnz * 4);
    int* n_list = (int*)p; p = align256(p + (size_t)nnz * 4);
    int* eoff   = (int*)p; p = align256(p + (size_t)(N_EDGES + 1) * 4);
    int* noff   = (int*)p; p = align256(p + (size_t)(N_NODES + 1) * 4);
    int* Ceh    = (int*)p;                              // Ceh+Cnh contiguous
    int* Cnh    = Ceh + NB;
    p = align256((char*)(Cnh + NB));
    int* Cecur  = (int*)p; p = align256(p + NB * 4);
    int* Cncur  = (int*)p; p = align256(p + NB * 4);
    unsigned int* Whu = (unsigned int*)p; p = align256(p + (size_t)C * C / 2 * 4);
    size_t needed = (size_t)(p - (char*)d_ws);

    if (ws_size < needed) {
        float* m = (float*)d_ws;
        hipMemsetAsync(x1, 0, (size_t)N_EDGES * C * sizeof(float), stream);
        hipMemsetAsync(m,  0, (size_t)N_NODES * C * sizeof(float), stream);
        int blocks = (nnz + 7) / 8;
        scatter_rows<<<blocks, 256, 0, stream>>>((const float4*)x0, nidx, eidx, x1, nnz);
        scatter_rows<<<blocks, 256, 0, stream>>>((const float4*)x1, eidx, nidx, m, nnz);
        gin_gemm<<<N_NODES / 32, 256, 0, stream>>>(x0, m, W, b, out0);
        return;
    }

    int pblocks = (nnz + 4095) / 4096;

    // ---- fused pre-pass: bf16 conversions + zero coarse hist ----
    conv_all<<<X0_BLOCKS + C * C / 2 / 256, 256, 0, stream>>>(
        (const float2*)x0, (const float2*)W, x0h, Whu, Ceh);

    // ---- CSR front-end: one cooperative kernel (indices stay in registers) ----
    {
        void* args[] = { (void*)&nidx, (void*)&eidx, (void*)&Ceh, (void*)&Cnh,
                         (void*)&Cecur, (void*)&Cncur, (void*)&pe, (void*)&pn,
                         (void*)&nnz };
        hipError_t err = hipLaunchCooperativeKernel(
            (const void*)csr_front, dim3(pblocks), dim3(256), args, 0, stream);
        if (err != hipSuccess) {
            // fallback: 3-kernel non-cooperative path
            coarse_hist<<<pblocks, 256, 0, stream>>>(nidx, eidx, Ceh, Cnh, nnz);
            coarse_scan<<<1, 256, 0, stream>>>(Ceh, Cnh, Cecur, Cncur);
            partition_kernel<<<pblocks, 256, 0, stream>>>(
                nidx, eidx, Cecur, Cncur, pe, pn, nnz);
        }
    }

    bucket_scatter_ex<<<2 * NB, 256, 0, stream>>>(
        pe, pn, Cecur, Cncur, e_list, n_list, eoff, noff);

    // ---- step 1: x1 (fp32 out) + x1h (bf16) ----
    seg_sum<<<(N_EDGES * 64 + 255) / 256, 256, 0, stream>>>(
        x0h, e_list, eoff, (float2*)x1, x1h, N_EDGES);

    // ---- steps 2+3 fused ----
    gin_fused<<<N_NODES / 32, 256, 0, stream>>>(
        x0h, x1h, n_list, noff,
        (const unsigned short*)Whu, b, out0);
}

// Round 11
// 252.947 us; speedup vs baseline: 1.2467x; 1.2467x over previous
//
#include <hip/hip_runtime.h>
#include <stdint.h>

#define N_NODES 100000
#define N_EDGES 50000
#define C 128
#define NB 196        // coarse buckets: ceil(50000/256) == ceil(100000/512)
#define CAP 12288     // LDS staging entries per bucket (48KB)
#define X0_BLOCKS 25000   // N_NODES*C/2 / 256
#define WBLOCKS 32        // C*C/2 / 256
#define PCHUNK 8192       // partition chunk per block

typedef short short8 __attribute__((ext_vector_type(8)));   // 8 bf16 (4 VGPRs)
typedef float f32x4  __attribute__((ext_vector_type(4)));

// ---------- bf16 helpers ----------
__device__ __forceinline__ unsigned int bf16rne(float f) {
    unsigned int u = __float_as_uint(f);
    return (u + 0x7FFFu + ((u >> 16) & 1u)) >> 16;    // finite inputs only
}
__device__ __forceinline__ unsigned int pk_bf16(float x, float y) {
    return (bf16rne(y) << 16) | bf16rne(x);
}
__device__ __forceinline__ float bf_lo(unsigned int u) { return __uint_as_float(u << 16); }
__device__ __forceinline__ float bf_hi(unsigned int u) { return __uint_as_float(u & 0xFFFF0000u); }

// ---------- merged pre-pass: x0->bf16 | W->bf16 | coarse histogram ----------
// Block ranges: [0, X0_BLOCKS) convert x0; [X0_BLOCKS, X0_BLOCKS+WBLOCKS) convert W;
// rest do the LDS-privatized coarse histogram (Ceh/Cnh pre-zeroed by memset).
__global__ __launch_bounds__(256) void conv_hist(
    const float2* __restrict__ x0, const float2* __restrict__ W,
    unsigned int* __restrict__ x0h, unsigned int* __restrict__ Whu,
    const int* __restrict__ nidx, const int* __restrict__ eidx,
    int* __restrict__ Ceh, int* __restrict__ Cnh, int nnz)
{
    __shared__ int he[NB], hn[NB];
    int bid = blockIdx.x, t = threadIdx.x;
    if (bid < X0_BLOCKS) {
        int i = bid * 256 + t;
        float2 v = x0[i];
        x0h[i] = pk_bf16(v.x, v.y);
        return;
    }
    if (bid < X0_BLOCKS + WBLOCKS) {
        int i = (bid - X0_BLOCKS) * 256 + t;
        float2 v = W[i];
        Whu[i] = pk_bf16(v.x, v.y);
        return;
    }
    int chunk0 = (bid - X0_BLOCKS - WBLOCKS) * PCHUNK;
    for (int k = t; k < NB; k += 256) { he[k] = 0; hn[k] = 0; }
    __syncthreads();
#pragma unroll 4
    for (int j = 0; j < PCHUNK / 256; ++j) {
        int i = chunk0 + j * 256 + t;
        if (i < nnz) {
            atomicAdd(&he[eidx[i] >> 8], 1);
            atomicAdd(&hn[nidx[i] >> 9], 1);
        }
    }
    __syncthreads();
    for (int k = t; k < NB; k += 256) {
        if (he[k]) atomicAdd(&Ceh[k], he[k]);
        if (hn[k]) atomicAdd(&Cnh[k], hn[k]);
    }
}

// ---------------- tiny scan: coarse counts -> bucket base cursors ----------------
__global__ __launch_bounds__(256) void coarse_scan(
    const int* __restrict__ Ceh, const int* __restrict__ Cnh,
    int* __restrict__ Cecur, int* __restrict__ Cncur)
{
    __shared__ int s[256];
    int t = threadIdx.x;
    int v = (t < NB) ? Ceh[t] : 0;
    s[t] = v; __syncthreads();
    for (int d = 1; d < 256; d <<= 1) {
        int u = (t >= d) ? s[t - d] : 0;
        __syncthreads(); s[t] += u; __syncthreads();
    }
    if (t < NB) Cecur[t] = s[t] - v;
    __syncthreads();
    v = (t < NB) ? Cnh[t] : 0;
    s[t] = v; __syncthreads();
    for (int d = 1; d < 256; d <<= 1) {
        int u = (t >= d) ? s[t - d] : 0;
        __syncthreads(); s[t] += u; __syncthreads();
    }
    if (t < NB) Cncur[t] = s[t] - v;
}

// ---------------- phase B1: partition into coarse buckets, 4B packed pairs ----
// e-side pair: (e & 255) | (n << 8) ; n-side pair: (n & 511) | (e << 9)
__global__ __launch_bounds__(256) void partition_kernel(
    const int* __restrict__ nidx, const int* __restrict__ eidx,
    int* __restrict__ Cecur, int* __restrict__ Cncur,
    unsigned int* __restrict__ pe, unsigned int* __restrict__ pn, int nnz)
{
    __shared__ int he[NB], hn[NB], be[NB], bn[NB];
    int t = threadIdx.x;
    int chunk0 = blockIdx.x * PCHUNK;
    for (int k = t; k < NB; k += 256) { he[k] = 0; hn[k] = 0; }
    __syncthreads();
#pragma unroll 4
    for (int j = 0; j < PCHUNK / 256; ++j) {
        int i = chunk0 + j * 256 + t;
        if (i < nnz) {
            atomicAdd(&he[eidx[i] >> 8], 1);
            atomicAdd(&hn[nidx[i] >> 9], 1);
        }
    }
    __syncthreads();
    for (int k = t; k < NB; k += 256) {
        be[k] = atomicAdd(&Cecur[k], he[k]);
        bn[k] = atomicAdd(&Cncur[k], hn[k]);
        he[k] = 0; hn[k] = 0;
    }
    __syncthreads();
#pragma unroll 4
    for (int j = 0; j < PCHUNK / 256; ++j) {
        int i = chunk0 + j * 256 + t;
        if (i < nnz) {
            int e = eidx[i], n = nidx[i];
            int re = atomicAdd(&he[e >> 8], 1);
            pe[be[e >> 8] + re] = (unsigned int)((e & 255) | (n << 8));
            int rn = atomicAdd(&hn[n >> 9], 1);
            pn[bn[n >> 9] + rn] = (unsigned int)((n & 511) | (e << 9));
        }
    }
}

// ---------------- phase B2: fine hist + scan + scatter, all in LDS ----------------
// After partition, Cecur[b] / Cncur[b] hold END offsets of bucket b.
__global__ __launch_bounds__(256) void bucket_scatter_ex(
    const unsigned int* __restrict__ pe, const unsigned int* __restrict__ pn,
    const int* __restrict__ Cecur, const int* __restrict__ Cncur,
    int* __restrict__ e_list, int* __restrict__ n_list,
    int* __restrict__ eoff, int* __restrict__ noff)
{
    __shared__ int cnt[512], cur[512], s[256];
    __shared__ int vals[CAP];
    bool eside = blockIdx.x < NB;
    int b = eside ? blockIdx.x : blockIdx.x - NB;
    const unsigned int* pairs = eside ? pe : pn;
    const int* endarr         = eside ? Cecur : Cncur;
    int* out                  = eside ? e_list : n_list;
    int* off                  = eside ? eoff : noff;
    int shift = eside ? 8 : 9;
    int mask  = (1 << shift) - 1;
    int kpb   = 1 << shift;
    int nkeys = eside ? N_EDGES : N_NODES;
    int key0 = b * kpb;
    int nk = nkeys - key0; if (nk > kpb) nk = kpb;
    if (nk <= 0) return;
    int start = (b == 0) ? 0 : endarr[b - 1];
    int end   = endarr[b];
    int t = threadIdx.x;

    for (int k = t; k < nk; k += 256) cnt[k] = 0;
    __syncthreads();
    for (int i = start + t; i < end; i += 256)
        atomicAdd(&cnt[(int)(pairs[i] & mask)], 1);
    __syncthreads();
    int k0 = 2 * t, k1 = 2 * t + 1;
    int c0 = (k0 < nk) ? cnt[k0] : 0;
    int c1 = (k1 < nk) ? cnt[k1] : 0;
    int local = c0 + c1;
    s[t] = local; __syncthreads();
    for (int d = 1; d < 256; d <<= 1) {
        int u = (t >= d) ? s[t - d] : 0;
        __syncthreads(); s[t] += u; __syncthreads();
    }
    int excl = s[t] - local;
    if (k0 < nk) { cur[k0] = excl;      off[key0 + k0] = start + excl; }
    if (k1 < nk) { cur[k1] = excl + c0; off[key0 + k1] = start + excl + c0; }
    if (b == NB - 1 && t == 0) off[nkeys] = end;
    __syncthreads();
    for (int i = start + t; i < end; i += 256) {
        unsigned int p = pairs[i];
        int key = (int)(p & mask);
        int val = (int)(p >> shift);
        int pos = atomicAdd(&cur[key], 1);
        if (pos < CAP) vals[pos] = val;
        else out[start + pos] = val;
    }
    __syncthreads();
    int sz = end - start; if (sz > CAP) sz = CAP;
    for (int j = t; j < sz; j += 256) out[start + j] = vals[j];
}

// ---------------- 8-deep MLP gather-sum of packed-bf16 rows ----------------
__device__ __forceinline__ float2 gather_bf16_rows(
    const unsigned int* __restrict__ src, const int* __restrict__ list,
    int s0, int s1, int lane)
{
    float ax0=0,ay0=0,ax1=0,ay1=0,ax2=0,ay2=0,ax3=0,ay3=0;
    float ax4=0,ay4=0,ax5=0,ay5=0,ax6=0,ay6=0,ax7=0,ay7=0;
    for (int base = s0; base < s1; base += 64) {
        int cnt = s1 - base; if (cnt > 64) cnt = 64;
        int my = (lane < cnt) ? list[base + lane] : 0;
        int j = 0;
        for (; j + 8 <= cnt; j += 8) {
            int g0 = __shfl(my, j+0), g1 = __shfl(my, j+1);
            int g2 = __shfl(my, j+2), g3 = __shfl(my, j+3);
            int g4 = __shfl(my, j+4), g5 = __shfl(my, j+5);
            int g6 = __shfl(my, j+6), g7 = __shfl(my, j+7);
            unsigned int u0 = src[(size_t)g0 * 64 + lane];
            unsigned int u1 = src[(size_t)g1 * 64 + lane];
            unsigned int u2 = src[(size_t)g2 * 64 + lane];
            unsigned int u3 = src[(size_t)g3 * 64 + lane];
            unsigned int u4 = src[(size_t)g4 * 64 + lane];
            unsigned int u5 = src[(size_t)g5 * 64 + lane];
            unsigned int u6 = src[(size_t)g6 * 64 + lane];
            unsigned int u7 = src[(size_t)g7 * 64 + lane];
            ax0 += bf_lo(u0); ay0 += bf_hi(u0);  ax1 += bf_lo(u1); ay1 += bf_hi(u1);
            ax2 += bf_lo(u2); ay2 += bf_hi(u2);  ax3 += bf_lo(u3); ay3 += bf_hi(u3);
            ax4 += bf_lo(u4); ay4 += bf_hi(u4);  ax5 += bf_lo(u5); ay5 += bf_hi(u5);
            ax6 += bf_lo(u6); ay6 += bf_hi(u6);  ax7 += bf_lo(u7); ay7 += bf_hi(u7);
        }
        for (; j < cnt; ++j) {
            int g = __shfl(my, j);
            unsigned int u = src[(size_t)g * 64 + lane];
            ax0 += bf_lo(u); ay0 += bf_hi(u);
        }
    }
    ax0+=ax1; ay0+=ay1; ax2+=ax3; ay2+=ay3; ax4+=ax5; ay4+=ay5; ax6+=ax7; ay6+=ay7;
    ax0+=ax2; ay0+=ay2; ax4+=ax6; ay4+=ay6;
    ax0+=ax4; ay0+=ay4;
    return make_float2(ax0, ay0);
}

// ---------------- step 1: x1[e] = sum_{n in e} x0[n] (+ bf16 copy) ----------------
__global__ __launch_bounds__(256) void seg_sum(
    const unsigned int* __restrict__ x0h, const int* __restrict__ list,
    const int* __restrict__ off, float2* __restrict__ x1,
    unsigned int* __restrict__ x1h, int nseg)
{
    int wid  = (blockIdx.x * 256 + threadIdx.x) >> 6;
    int lane = threadIdx.x & 63;
    if (wid >= nseg) return;
    float2 acc = gather_bf16_rows(x0h, list, off[wid], off[wid + 1], lane);
    x1 [(size_t)wid * 64 + lane] = acc;
    x1h[(size_t)wid * 64 + lane] = pk_bf16(acc.x, acc.y);
}

// ---------------- steps 2+3 fused: gather + MFMA GEMM ----------------
__global__ __launch_bounds__(256) void gin_fused(
    const unsigned int* __restrict__ x0h, const unsigned int* __restrict__ x1h,
    const int* __restrict__ n_list, const int* __restrict__ noff,
    const unsigned short* __restrict__ Wh, const float* __restrict__ b,
    float* __restrict__ out)
{
    __shared__ __align__(16) unsigned short ins[32][136];  // bf16, +16B pad/row
    int t = threadIdx.x;
    int lane = t & 63, w = t >> 6;
    int row0 = blockIdx.x * 32;

    for (int r = w * 8; r < w * 8 + 8; ++r) {
        int node = row0 + r;
        unsigned int bu = x0h[(size_t)node * 64 + lane];
        float2 g = gather_bf16_rows(x1h, n_list, noff[node], noff[node + 1], lane);
        g.x += bf_lo(bu); g.y += bf_hi(bu);
        *(unsigned int*)&ins[r][lane * 2] = pk_bf16(g.x, g.y);
    }
    __syncthreads();

    int mt  = w & 1;            // M-tile (16 rows)
    int ntb = (w >> 1) * 4;     // first of 4 N-tiles
    int l15  = lane & 15;
    int koff = (lane >> 4) * 8;
    int arow = mt * 16 + l15;

    f32x4 acc0 = {0,0,0,0}, acc1 = {0,0,0,0}, acc2 = {0,0,0,0}, acc3 = {0,0,0,0};
#pragma unroll
    for (int kt = 0; kt < C; kt += 32) {
        short8 a = *(const short8*)&ins[arow][kt + koff];
        short8 b0 = *(const short8*)&Wh[(size_t)((ntb + 0) * 16 + l15) * C + kt + koff];
        short8 b1 = *(const short8*)&Wh[(size_t)((ntb + 1) * 16 + l15) * C + kt + koff];
        short8 b2 = *(const short8*)&Wh[(size_t)((ntb + 2) * 16 + l15) * C + kt + koff];
        short8 b3 = *(const short8*)&Wh[(size_t)((ntb + 3) * 16 + l15) * C + kt + koff];
        acc0 = __builtin_amdgcn_mfma_f32_16x16x32_bf16(a, b0, acc0, 0, 0, 0);
        acc1 = __builtin_amdgcn_mfma_f32_16x16x32_bf16(a, b1, acc1, 0, 0, 0);
        acc2 = __builtin_amdgcn_mfma_f32_16x16x32_bf16(a, b2, acc2, 0, 0, 0);
        acc3 = __builtin_amdgcn_mfma_f32_16x16x32_bf16(a, b3, acc3, 0, 0, 0);
    }

    int drow = row0 + mt * 16 + (lane >> 4) * 4;
#pragma unroll
    for (int n = 0; n < 4; ++n) {
        f32x4 accv = (n == 0) ? acc0 : (n == 1) ? acc1 : (n == 2) ? acc2 : acc3;
        int colg = (ntb + n) * 16 + l15;
        float bias = b[colg];
#pragma unroll
        for (int j = 0; j < 4; ++j)
            out[(size_t)(drow + j) * C + colg] = accv[j] + bias;
    }
}

// ---------------- fallback atomic path ----------------
__global__ __launch_bounds__(256) void scatter_rows(
    const float4* __restrict__ src, const int* __restrict__ gather_idx,
    const int* __restrict__ scatter_idx, float* __restrict__ dst, int nnz)
{
    int gid = blockIdx.x * 256 + threadIdx.x;
    int row = gid >> 5, lane = gid & 31;
    if (row >= nnz) return;
    float4 v = src[(size_t)gather_idx[row] * 32 + lane];
    float* d = dst + (size_t)scatter_idx[row] * C + lane * 4;
    atomicAdd(d + 0, v.x); atomicAdd(d + 1, v.y);
    atomicAdd(d + 2, v.z); atomicAdd(d + 3, v.w);
}

__global__ __launch_bounds__(256) void gin_gemm(
    const float* __restrict__ x0, const float* __restrict__ m,
    const float* __restrict__ W, const float* __restrict__ b,
    float* __restrict__ out)
{
    __shared__ float Ws[32][129];
    __shared__ float insf[32][33];
    int t = threadIdx.x;
    int col = t & 127, rg = t >> 7;
    int row0 = blockIdx.x * 32;
    float acc[16];
#pragma unroll
    for (int r = 0; r < 16; ++r) acc[r] = 0.f;
    float bias = b[col];
    for (int kt = 0; kt < C; kt += 32) {
#pragma unroll
        for (int j = 0; j < 16; ++j) {
            int i = j * 256 + t, wc = i >> 5, kl = i & 31;
            Ws[kl][wc] = W[(size_t)wc * C + kt + kl];
        }
#pragma unroll
        for (int j = 0; j < 4; ++j) {
            int i = j * 256 + t, r = i >> 5, kl = i & 31;
            size_t gi = (size_t)(row0 + r) * C + kt + kl;
            insf[r][kl] = x0[gi] + m[gi];
        }
        __syncthreads();
#pragma unroll
        for (int kl = 0; kl < 32; ++kl) {
            float wv = Ws[kl][col];
#pragma unroll
            for (int r = 0; r < 16; ++r)
                acc[r] += insf[rg * 16 + r][kl] * wv;
        }
        __syncthreads();
    }
#pragma unroll
    for (int r = 0; r < 16; ++r)
        out[(size_t)(row0 + rg * 16 + r) * C + col] = acc[r] + bias;
}

extern "C" void kernel_launch(void* const* d_in, const int* in_sizes, int n_in,
                              void* d_out, int out_size, void* d_ws, size_t ws_size,
                              hipStream_t stream) {
    const float* x0 = (const float*)d_in[0];
    const int* nidx = (const int*)d_in[1];
    const int* eidx = (const int*)d_in[2];
    const float* W  = (const float*)d_in[3];
    const float* b  = (const float*)d_in[4];

    float* out0 = (float*)d_out;
    float* x1   = out0 + (size_t)N_NODES * C;
    int nnz = in_sizes[1];

    // ---- workspace layout, 256B-aligned feature regions ----
    auto align256 = [](char* q) {
        return (char*)(((uintptr_t)q + 255) & ~(uintptr_t)255);
    };
    char* p = align256((char*)d_ws);
    unsigned int* pe = (unsigned int*)p; p = align256(p + (size_t)nnz * 4);  // 4B pairs
    unsigned int* pn = (unsigned int*)p; p = align256(p + (size_t)nnz * 4);
    unsigned int* x0h = (unsigned int*)p; p = align256(p + (size_t)N_NODES * 64 * 4);
    unsigned int* x1h = (unsigned int*)p; p = align256(p + (size_t)N_EDGES * 64 * 4);
    int* e_list = (int*)p; p = align256(p + (size_t)nnz * 4);
    int* n_list = (int*)p; p = align256(p + (size_t)nnz * 4);
    int* eoff   = (int*)p; p = align256(p + (size_t)(N_EDGES + 1) * 4);
    int* noff   = (int*)p; p = align256(p + (size_t)(N_NODES + 1) * 4);
    int* Ceh    = (int*)p;                              // Ceh+Cnh contiguous (one memset)
    int* Cnh    = Ceh + NB;
    p = align256((char*)(Cnh + NB));
    int* Cecur  = (int*)p; p = align256(p + NB * 4);
    int* Cncur  = (int*)p; p = align256(p + NB * 4);
    unsigned int* Whu = (unsigned int*)p; p = align256(p + (size_t)C * C / 2 * 4);
    size_t needed = (size_t)(p - (char*)d_ws);

    if (ws_size < needed) {
        float* m = (float*)d_ws;
        hipMemsetAsync(x1, 0, (size_t)N_EDGES * C * sizeof(float), stream);
        hipMemsetAsync(m,  0, (size_t)N_NODES * C * sizeof(float), stream);
        int blocks = (nnz + 7) / 8;
        scatter_rows<<<blocks, 256, 0, stream>>>((const float4*)x0, nidx, eidx, x1, nnz);
        scatter_rows<<<blocks, 256, 0, stream>>>((const float4*)x1, eidx, nidx, m, nnz);
        gin_gemm<<<N_NODES / 32, 256, 0, stream>>>(x0, m, W, b, out0);
        return;
    }

    int pblocks = (nnz + PCHUNK - 1) / PCHUNK;

    // ---- merged pre-pass: conversions + coarse histogram (Ceh/Cnh zeroed first) ----
    hipMemsetAsync(Ceh, 0, 2 * NB * sizeof(int), stream);
    conv_hist<<<X0_BLOCKS + WBLOCKS + pblocks, 256, 0, stream>>>(
        (const float2*)x0, (const float2*)W, x0h, Whu, nidx, eidx, Ceh, Cnh, nnz);

    // ---- CSR build: tiny scan -> partition -> per-bucket LDS sort ----
    coarse_scan<<<1, 256, 0, stream>>>(Ceh, Cnh, Cecur, Cncur);
    partition_kernel<<<pblocks, 256, 0, stream>>>(
        nidx, eidx, Cecur, Cncur, pe, pn, nnz);
    bucket_scatter_ex<<<2 * NB, 256, 0, stream>>>(
        pe, pn, Cecur, Cncur, e_list, n_list, eoff, noff);

    // ---- step 1: x1 (fp32 out) + x1h (bf16) ----
    seg_sum<<<(N_EDGES * 64 + 255) / 256, 256, 0, stream>>>(
        x0h, e_list, eoff, (float2*)x1, x1h, N_EDGES);

    // ---- steps 2+3 fused ----
    gin_fused<<<N_NODES / 32, 256, 0, stream>>>(
        x0h, x1h, n_list, noff,
        (const unsigned short*)Whu, b, out0);
}

// Round 12
// 245.372 us; speedup vs baseline: 1.2852x; 1.0309x over previous
//
#include <hip/hip_runtime.h>
#include <stdint.h>

#define N_NODES 100000
#define N_EDGES 50000
#define C 128
#define NB 196        // coarse buckets: ceil(50000/256) == ceil(100000/512)
#define CAP 12288     // LDS staging entries per bucket (48KB)
#define X0_BLOCKS 25000   // N_NODES*C/2 / 256
#define WBLOCKS 32        // C*C/2 / 256
#define PCHUNK 8192       // partition chunk per block

typedef short short8 __attribute__((ext_vector_type(8)));   // 8 bf16 (4 VGPRs)
typedef float f32x4  __attribute__((ext_vector_type(4)));

// ---------- bf16 helpers ----------
__device__ __forceinline__ unsigned int bf16rne(float f) {
    unsigned int u = __float_as_uint(f);
    return (u + 0x7FFFu + ((u >> 16) & 1u)) >> 16;    // finite inputs only
}
__device__ __forceinline__ unsigned int pk_bf16(float x, float y) {
    return (bf16rne(y) << 16) | bf16rne(x);
}
__device__ __forceinline__ float bf_lo(unsigned int u) { return __uint_as_float(u << 16); }
__device__ __forceinline__ float bf_hi(unsigned int u) { return __uint_as_float(u & 0xFFFF0000u); }

// ---------- merged pre-pass: x0->bf16 | W->bf16 | coarse histogram ----------
__global__ __launch_bounds__(256) void conv_hist(
    const float2* __restrict__ x0, const float2* __restrict__ W,
    unsigned int* __restrict__ x0h, unsigned int* __restrict__ Whu,
    const int* __restrict__ nidx, const int* __restrict__ eidx,
    int* __restrict__ Ceh, int* __restrict__ Cnh, int nnz)
{
    __shared__ int he[NB], hn[NB];
    int bid = blockIdx.x, t = threadIdx.x;
    if (bid < X0_BLOCKS) {
        int i = bid * 256 + t;
        float2 v = x0[i];
        x0h[i] = pk_bf16(v.x, v.y);
        return;
    }
    if (bid < X0_BLOCKS + WBLOCKS) {
        int i = (bid - X0_BLOCKS) * 256 + t;
        float2 v = W[i];
        Whu[i] = pk_bf16(v.x, v.y);
        return;
    }
    int chunk0 = (bid - X0_BLOCKS - WBLOCKS) * PCHUNK;
    for (int k = t; k < NB; k += 256) { he[k] = 0; hn[k] = 0; }
    __syncthreads();
#pragma unroll 4
    for (int j = 0; j < PCHUNK / 256; ++j) {
        int i = chunk0 + j * 256 + t;
        if (i < nnz) {
            atomicAdd(&he[eidx[i] >> 8], 1);
            atomicAdd(&hn[nidx[i] >> 9], 1);
        }
    }
    __syncthreads();
    for (int k = t; k < NB; k += 256) {
        if (he[k]) atomicAdd(&Ceh[k], he[k]);
        if (hn[k]) atomicAdd(&Cnh[k], hn[k]);
    }
}

// ---------------- tiny scan: coarse counts -> bucket base cursors ----------------
__global__ __launch_bounds__(256) void coarse_scan(
    const int* __restrict__ Ceh, const int* __restrict__ Cnh,
    int* __restrict__ Cecur, int* __restrict__ Cncur)
{
    __shared__ int s[256];
    int t = threadIdx.x;
    int v = (t < NB) ? Ceh[t] : 0;
    s[t] = v; __syncthreads();
    for (int d = 1; d < 256; d <<= 1) {
        int u = (t >= d) ? s[t - d] : 0;
        __syncthreads(); s[t] += u; __syncthreads();
    }
    if (t < NB) Cecur[t] = s[t] - v;
    __syncthreads();
    v = (t < NB) ? Cnh[t] : 0;
    s[t] = v; __syncthreads();
    for (int d = 1; d < 256; d <<= 1) {
        int u = (t >= d) ? s[t - d] : 0;
        __syncthreads(); s[t] += u; __syncthreads();
    }
    if (t < NB) Cncur[t] = s[t] - v;
}

// ---------------- phase B1: partition into coarse buckets, 4B packed pairs ----
__global__ __launch_bounds__(256) void partition_kernel(
    const int* __restrict__ nidx, const int* __restrict__ eidx,
    int* __restrict__ Cecur, int* __restrict__ Cncur,
    unsigned int* __restrict__ pe, unsigned int* __restrict__ pn, int nnz)
{
    __shared__ int he[NB], hn[NB], be[NB], bn[NB];
    int t = threadIdx.x;
    int chunk0 = blockIdx.x * PCHUNK;
    for (int k = t; k < NB; k += 256) { he[k] = 0; hn[k] = 0; }
    __syncthreads();
#pragma unroll 4
    for (int j = 0; j < PCHUNK / 256; ++j) {
        int i = chunk0 + j * 256 + t;
        if (i < nnz) {
            atomicAdd(&he[eidx[i] >> 8], 1);
            atomicAdd(&hn[nidx[i] >> 9], 1);
        }
    }
    __syncthreads();
    for (int k = t; k < NB; k += 256) {
        be[k] = atomicAdd(&Cecur[k], he[k]);
        bn[k] = atomicAdd(&Cncur[k], hn[k]);
        he[k] = 0; hn[k] = 0;
    }
    __syncthreads();
#pragma unroll 4
    for (int j = 0; j < PCHUNK / 256; ++j) {
        int i = chunk0 + j * 256 + t;
        if (i < nnz) {
            int e = eidx[i], n = nidx[i];
            int re = atomicAdd(&he[e >> 8], 1);
            pe[be[e >> 8] + re] = (unsigned int)((e & 255) | (n << 8));
            int rn = atomicAdd(&hn[n >> 9], 1);
            pn[bn[n >> 9] + rn] = (unsigned int)((n & 511) | (e << 9));
        }
    }
}

// ---------------- phase B2: fine hist + scan + scatter, all in LDS ----------------
__global__ __launch_bounds__(256) void bucket_scatter_ex(
    const unsigned int* __restrict__ pe, const unsigned int* __restrict__ pn,
    const int* __restrict__ Cecur, const int* __restrict__ Cncur,
    int* __restrict__ e_list, int* __restrict__ n_list,
    int* __restrict__ eoff, int* __restrict__ noff)
{
    __shared__ int cnt[512], cur[512], s[256];
    __shared__ int vals[CAP];
    bool eside = blockIdx.x < NB;
    int b = eside ? blockIdx.x : blockIdx.x - NB;
    const unsigned int* pairs = eside ? pe : pn;
    const int* endarr         = eside ? Cecur : Cncur;
    int* out                  = eside ? e_list : n_list;
    int* off                  = eside ? eoff : noff;
    int shift = eside ? 8 : 9;
    int mask  = (1 << shift) - 1;
    int kpb   = 1 << shift;
    int nkeys = eside ? N_EDGES : N_NODES;
    int key0 = b * kpb;
    int nk = nkeys - key0; if (nk > kpb) nk = kpb;
    if (nk <= 0) return;
    int start = (b == 0) ? 0 : endarr[b - 1];
    int end   = endarr[b];
    int t = threadIdx.x;

    for (int k = t; k < nk; k += 256) cnt[k] = 0;
    __syncthreads();
    for (int i = start + t; i < end; i += 256)
        atomicAdd(&cnt[(int)(pairs[i] & mask)], 1);
    __syncthreads();
    int k0 = 2 * t, k1 = 2 * t + 1;
    int c0 = (k0 < nk) ? cnt[k0] : 0;
    int c1 = (k1 < nk) ? cnt[k1] : 0;
    int local = c0 + c1;
    s[t] = local; __syncthreads();
    for (int d = 1; d < 256; d <<= 1) {
        int u = (t >= d) ? s[t - d] : 0;
        __syncthreads(); s[t] += u; __syncthreads();
    }
    int excl = s[t] - local;
    if (k0 < nk) { cur[k0] = excl;      off[key0 + k0] = start + excl; }
    if (k1 < nk) { cur[k1] = excl + c0; off[key0 + k1] = start + excl + c0; }
    if (b == NB - 1 && t == 0) off[nkeys] = end;
    __syncthreads();
    for (int i = start + t; i < end; i += 256) {
        unsigned int p = pairs[i];
        int key = (int)(p & mask);
        int val = (int)(p >> shift);
        int pos = atomicAdd(&cur[key], 1);
        if (pos < CAP) vals[pos] = val;
        else out[start + pos] = val;
    }
    __syncthreads();
    int sz = end - start; if (sz > CAP) sz = CAP;
    for (int j = t; j < sz; j += 256) out[start + j] = vals[j];
}

// ---------------- 8-deep MLP gather-sum of packed-bf16 rows ----------------
__device__ __forceinline__ float2 gather_bf16_rows(
    const unsigned int* __restrict__ src, const int* __restrict__ list,
    int s0, int s1, int lane)
{
    float ax0=0,ay0=0,ax1=0,ay1=0,ax2=0,ay2=0,ax3=0,ay3=0;
    float ax4=0,ay4=0,ax5=0,ay5=0,ax6=0,ay6=0,ax7=0,ay7=0;
    for (int base = s0; base < s1; base += 64) {
        int cnt = s1 - base; if (cnt > 64) cnt = 64;
        int my = (lane < cnt) ? list[base + lane] : 0;
        int j = 0;
        for (; j + 8 <= cnt; j += 8) {
            int g0 = __shfl(my, j+0), g1 = __shfl(my, j+1);
            int g2 = __shfl(my, j+2), g3 = __shfl(my, j+3);
            int g4 = __shfl(my, j+4), g5 = __shfl(my, j+5);
            int g6 = __shfl(my, j+6), g7 = __shfl(my, j+7);
            unsigned int u0 = src[(size_t)g0 * 64 + lane];
            unsigned int u1 = src[(size_t)g1 * 64 + lane];
            unsigned int u2 = src[(size_t)g2 * 64 + lane];
            unsigned int u3 = src[(size_t)g3 * 64 + lane];
            unsigned int u4 = src[(size_t)g4 * 64 + lane];
            unsigned int u5 = src[(size_t)g5 * 64 + lane];
            unsigned int u6 = src[(size_t)g6 * 64 + lane];
            unsigned int u7 = src[(size_t)g7 * 64 + lane];
            ax0 += bf_lo(u0); ay0 += bf_hi(u0);  ax1 += bf_lo(u1); ay1 += bf_hi(u1);
            ax2 += bf_lo(u2); ay2 += bf_hi(u2);  ax3 += bf_lo(u3); ay3 += bf_hi(u3);
            ax4 += bf_lo(u4); ay4 += bf_hi(u4);  ax5 += bf_lo(u5); ay5 += bf_hi(u5);
            ax6 += bf_lo(u6); ay6 += bf_hi(u6);  ax7 += bf_lo(u7); ay7 += bf_hi(u7);
        }
        for (; j < cnt; ++j) {
            int g = __shfl(my, j);
            unsigned int u = src[(size_t)g * 64 + lane];
            ax0 += bf_lo(u); ay0 += bf_hi(u);
        }
    }
    ax0+=ax1; ay0+=ay1; ax2+=ax3; ay2+=ay3; ax4+=ax5; ay4+=ay5; ax6+=ax7; ay6+=ay7;
    ax0+=ax2; ay0+=ay2; ax4+=ax6; ay4+=ay6;
    ax0+=ax4; ay0+=ay4;
    return make_float2(ax0, ay0);
}

// ---------------- step 1: x1[e] = sum_{n in e} x0[n] (+ bf16 copy) ----------------
__global__ __launch_bounds__(256) void seg_sum(
    const unsigned int* __restrict__ x0h, const int* __restrict__ list,
    const int* __restrict__ off, float2* __restrict__ x1,
    unsigned int* __restrict__ x1h, int nseg)
{
    int wid  = (blockIdx.x * 256 + threadIdx.x) >> 6;
    int lane = threadIdx.x & 63;
    if (wid >= nseg) return;
    float2 acc = gather_bf16_rows(x0h, list, off[wid], off[wid + 1], lane);
    x1 [(size_t)wid * 64 + lane] = acc;
    x1h[(size_t)wid * 64 + lane] = pk_bf16(acc.x, acc.y);
}

// ---------------- step 2: m-gather, IN PLACE into x0h ----------------
// One wave per node, no barriers. x0h[n] <- bf16(x0h[n] + sum_{e ∋ n} x1h[e]).
// Safe: after seg_sum, x0h row n is only ever read by this wave.
__global__ __launch_bounds__(256) void m_gather(
    unsigned int* __restrict__ x0h, const unsigned int* __restrict__ x1h,
    const int* __restrict__ n_list, const int* __restrict__ noff)
{
    int wid  = (blockIdx.x * 256 + threadIdx.x) >> 6;
    int lane = threadIdx.x & 63;
    if (wid >= N_NODES) return;
    unsigned int bu = x0h[(size_t)wid * 64 + lane];
    float2 g = gather_bf16_rows(x1h, n_list, noff[wid], noff[wid + 1], lane);
    g.x += bf_lo(bu); g.y += bf_hi(bu);
    x0h[(size_t)wid * 64 + lane] = pk_bf16(g.x, g.y);
}

// ---------------- step 3: pure MFMA GEMM, no LDS, no barriers ----------------
// Wave w of block handles 16 rows: out[rows] = mh[rows] @ Wh^T + b.
__global__ __launch_bounds__(256) void gin_gemm_mfma(
    const unsigned int* __restrict__ mh,   // bf16 rows (in-place updated x0h)
    const unsigned short* __restrict__ Wh, const float* __restrict__ b,
    float* __restrict__ out)
{
    int t = threadIdx.x;
    int lane = t & 63, w = t >> 6;
    int wrow0 = blockIdx.x * 64 + w * 16;
    if (wrow0 >= N_NODES) return;
    int l15  = lane & 15;
    int koff = (lane >> 4) * 8;
    const unsigned short* mrow = (const unsigned short*)mh + (size_t)(wrow0 + l15) * C;

    f32x4 acc[8];
#pragma unroll
    for (int n = 0; n < 8; ++n) acc[n] = (f32x4){0, 0, 0, 0};
#pragma unroll
    for (int kt = 0; kt < C; kt += 32) {
        short8 a = *(const short8*)&mrow[kt + koff];
#pragma unroll
        for (int n = 0; n < 8; ++n) {
            short8 bb = *(const short8*)&Wh[(size_t)(n * 16 + l15) * C + kt + koff];
            acc[n] = __builtin_amdgcn_mfma_f32_16x16x32_bf16(a, bb, acc[n], 0, 0, 0);
        }
    }
    int drow = wrow0 + (lane >> 4) * 4;
#pragma unroll
    for (int n = 0; n < 8; ++n) {
        int colg = n * 16 + l15;
        float bias = b[colg];
#pragma unroll
        for (int j = 0; j < 4; ++j)
            out[(size_t)(drow + j) * C + colg] = acc[n][j] + bias;
    }
}

// ---------------- fallback atomic path ----------------
__global__ __launch_bounds__(256) void scatter_rows(
    const float4* __restrict__ src, const int* __restrict__ gather_idx,
    const int* __restrict__ scatter_idx, float* __restrict__ dst, int nnz)
{
    int gid = blockIdx.x * 256 + threadIdx.x;
    int row = gid >> 5, lane = gid & 31;
    if (row >= nnz) return;
    float4 v = src[(size_t)gather_idx[row] * 32 + lane];
    float* d = dst + (size_t)scatter_idx[row] * C + lane * 4;
    atomicAdd(d + 0, v.x); atomicAdd(d + 1, v.y);
    atomicAdd(d + 2, v.z); atomicAdd(d + 3, v.w);
}

__global__ __launch_bounds__(256) void gin_gemm(
    const float* __restrict__ x0, const float* __restrict__ m,
    const float* __restrict__ W, const float* __restrict__ b,
    float* __restrict__ out)
{
    __shared__ float Ws[32][129];
    __shared__ float insf[32][33];
    int t = threadIdx.x;
    int col = t & 127, rg = t >> 7;
    int row0 = blockIdx.x * 32;
    float acc[16];
#pragma unroll
    for (int r = 0; r < 16; ++r) acc[r] = 0.f;
    float bias = b[col];
    for (int kt = 0; kt < C; kt += 32) {
#pragma unroll
        for (int j = 0; j < 16; ++j) {
            int i = j * 256 + t, wc = i >> 5, kl = i & 31;
            Ws[kl][wc] = W[(size_t)wc * C + kt + kl];
        }
#pragma unroll
        for (int j = 0; j < 4; ++j) {
            int i = j * 256 + t, r = i >> 5, kl = i & 31;
            size_t gi = (size_t)(row0 + r) * C + kt + kl;
            insf[r][kl] = x0[gi] + m[gi];
        }
        __syncthreads();
#pragma unroll
        for (int kl = 0; kl < 32; ++kl) {
            float wv = Ws[kl][col];
#pragma unroll
            for (int r = 0; r < 16; ++r)
                acc[r] += insf[rg * 16 + r][kl] * wv;
        }
        __syncthreads();
    }
#pragma unroll
    for (int r = 0; r < 16; ++r)
        out[(size_t)(row0 + rg * 16 + r) * C + col] = acc[r] + bias;
}

extern "C" void kernel_launch(void* const* d_in, const int* in_sizes, int n_in,
                              void* d_out, int out_size, void* d_ws, size_t ws_size,
                              hipStream_t stream) {
    const float* x0 = (const float*)d_in[0];
    const int* nidx = (const int*)d_in[1];
    const int* eidx = (const int*)d_in[2];
    const float* W  = (const float*)d_in[3];
    const float* b  = (const float*)d_in[4];

    float* out0 = (float*)d_out;
    float* x1   = out0 + (size_t)N_NODES * C;
    int nnz = in_sizes[1];

    // ---- workspace layout, 256B-aligned feature regions ----
    auto align256 = [](char* q) {
        return (char*)(((uintptr_t)q + 255) & ~(uintptr_t)255);
    };
    char* p = align256((char*)d_ws);
    unsigned int* pe = (unsigned int*)p; p = align256(p + (size_t)nnz * 4);  // 4B pairs
    unsigned int* pn = (unsigned int*)p; p = align256(p + (size_t)nnz * 4);
    unsigned int* x0h = (unsigned int*)p; p = align256(p + (size_t)N_NODES * 64 * 4);
    unsigned int* x1h = (unsigned int*)p; p = align256(p + (size_t)N_EDGES * 64 * 4);
    int* e_list = (int*)p; p = align256(p + (size_t)nnz * 4);
    int* n_list = (int*)p; p = align256(p + (size_t)nnz * 4);
    int* eoff   = (int*)p; p = align256(p + (size_t)(N_EDGES + 1) * 4);
    int* noff   = (int*)p; p = align256(p + (size_t)(N_NODES + 1) * 4);
    int* Ceh    = (int*)p;                              // Ceh+Cnh contiguous (one memset)
    int* Cnh    = Ceh + NB;
    p = align256((char*)(Cnh + NB));
    int* Cecur  = (int*)p; p = align256(p + NB * 4);
    int* Cncur  = (int*)p; p = align256(p + NB * 4);
    unsigned int* Whu = (unsigned int*)p; p = align256(p + (size_t)C * C / 2 * 4);
    size_t needed = (size_t)(p - (char*)d_ws);

    if (ws_size < needed) {
        float* m = (float*)d_ws;
        hipMemsetAsync(x1, 0, (size_t)N_EDGES * C * sizeof(float), stream);
        hipMemsetAsync(m,  0, (size_t)N_NODES * C * sizeof(float), stream);
        int blocks = (nnz + 7) / 8;
        scatter_rows<<<blocks, 256, 0, stream>>>((const float4*)x0, nidx, eidx, x1, nnz);
        scatter_rows<<<blocks, 256, 0, stream>>>((const float4*)x1, eidx, nidx, m, nnz);
        gin_gemm<<<N_NODES / 32, 256, 0, stream>>>(x0, m, W, b, out0);
        return;
    }

    int pblocks = (nnz + PCHUNK - 1) / PCHUNK;

    // ---- merged pre-pass: conversions + coarse histogram ----
    hipMemsetAsync(Ceh, 0, 2 * NB * sizeof(int), stream);
    conv_hist<<<X0_BLOCKS + WBLOCKS + pblocks, 256, 0, stream>>>(
        (const float2*)x0, (const float2*)W, x0h, Whu, nidx, eidx, Ceh, Cnh, nnz);

    // ---- CSR build: tiny scan -> partition -> per-bucket LDS sort ----
    coarse_scan<<<1, 256, 0, stream>>>(Ceh, Cnh, Cecur, Cncur);
    partition_kernel<<<pblocks, 256, 0, stream>>>(
        nidx, eidx, Cecur, Cncur, pe, pn, nnz);
    bucket_scatter_ex<<<2 * NB, 256, 0, stream>>>(
        pe, pn, Cecur, Cncur, e_list, n_list, eoff, noff);

    // ---- step 1: x1 (fp32 out) + x1h (bf16) ----
    seg_sum<<<(N_EDGES * 64 + 255) / 256, 256, 0, stream>>>(
        x0h, e_list, eoff, (float2*)x1, x1h, N_EDGES);

    // ---- step 2: m-gather in place (x0h becomes the GEMM input rows) ----
    m_gather<<<(N_NODES * 64 + 255) / 256, 256, 0, stream>>>(
        x0h, x1h, n_list, noff);

    // ---- step 3: out0 = mh @ W^T + b (pure MFMA, no LDS) ----
    gin_gemm_mfma<<<(N_NODES + 63) / 64, 256, 0, stream>>>(
        x0h, (const unsigned short*)Whu, b, out0);
}